// Round 16
// baseline (33.783 us; speedup 1.0000x reference)
//
#include <hip/hip_runtime.h>
#include <hip/hip_fp16.h>

// HalutMatmul forward on MI355X — phase-pure two-kernel split (round 16).
// Per row n: h[c][p] = sum_d I[n, c*9+d] * A[c][d][p]   (c=0..15, p=0..3)
//            code_c  = 4-level tree descent: bit_l = (h[c][l] > T[c*15 + node_l])
//            out[n][m] = sum_c L[m][c][code_c]
//
// R3-R15 all land 27-31us across 8 structures: the limiter is chip-scale
// phase serialization (all blocks lockstep: read-window -> LDS-window ->
// write-window; each pipe idles ~60% of wall). Split into phase-pure kernels,
// each saturating its own pipe with the whole chip:
//  K1 = R10's role-switch f64 hash (bit-exact codes), no LUT LDS, 16 waves/CU,
//       pure read-stream; codes nibble-packed via shfl -> 1MB coalesced.
//  K2 = R15's f16 LUT gather + swizzled transpose epilogue, codes from global,
//       pure LDS+write-stream.

#define NROWS (1024 * 128)

// ---------------------------------------------------------------- K1: codes
__global__ __launch_bounds__(256, 2) void halut_codes(
    const float* __restrict__ I,
    const float* __restrict__ A,
    const float* __restrict__ T,
    uint32_t* __restrict__ codes)      // [row] -> uint2 (16 codes, 4b each)
{
    __shared__ float    sStage[4][2304];   // wave-private: 16 rows x 144 f32
    __shared__ uint32_t sCodes[512];       // 256 rows x 2 u32

    const int tid  = threadIdx.x;
    const int w    = tid >> 6;
    const int lane = tid & 63;
    const int cB   = lane & 15;            // codebook
    const int g    = lane >> 4;            // row-in-pass

    // ---- per-lane constants: codebook cB's A and T in VGPRs (R10 verbatim) ----
    float Af[36];
    {
        const float4* ap4 = (const float4*)(A + cB * 36);   // 144B-aligned
        #pragma unroll
        for (int i = 0; i < 9; ++i) {
            const float4 v = ap4[i];
            Af[4*i+0] = v.x; Af[4*i+1] = v.y; Af[4*i+2] = v.z; Af[4*i+3] = v.w;
        }
    }
    float Tf[15];
    #pragma unroll
    for (int j = 0; j < 15; ++j) Tf[j] = T[cB * 15 + j];

    // ---- hash superphases: 4 x (stage 16 rows coalesced, 4 passes x 4 rows) ----
    const int wave_row0 = blockIdx.x * 256 + w * 64;
    const float4* Isrc = (const float4*)I;
    float4* st4 = (float4*)sStage[w];

    float4 nbuf[9];
    #pragma unroll
    for (int i = 0; i < 9; ++i)
        nbuf[i] = Isrc[(size_t)wave_row0 * 36 + i * 64 + lane];

    #pragma unroll
    for (int p16 = 0; p16 < 4; ++p16) {
        #pragma unroll
        for (int i = 0; i < 9; ++i) st4[i * 64 + lane] = nbuf[i];   // write-late
        if (p16 < 3) {                                               // issue-early
            #pragma unroll
            for (int i = 0; i < 9; ++i)
                nbuf[i] = Isrc[(size_t)(wave_row0 + (p16+1)*16) * 36 + i*64 + lane];
        }
        #pragma unroll
        for (int ps = 0; ps < 4; ++ps) {
            const int lr = ps * 4 + g;            // row 0..15 within chunk
            const float* xr = &sStage[w][lr * 144 + cB * 9];
            // f64 hash, FMA order of rounds 1-10 -> codes bit-identical
            double h0 = 0.0, h1 = 0.0, h2 = 0.0, h3 = 0.0;
            #pragma unroll
            for (int d = 0; d < 9; ++d) {
                const double x = (double)xr[d];
                h0 = fma(x, (double)Af[4*d+0], h0);
                h1 = fma(x, (double)Af[4*d+1], h1);
                h2 = fma(x, (double)Af[4*d+2], h2);
                h3 = fma(x, (double)Af[4*d+3], h3);
            }
            uint32_t mk = 0;
            mk |= (h0 > (double)Tf[0])  ?     1u : 0u;   // node 0  (level 0)
            mk |= (h1 > (double)Tf[1])  ?     2u : 0u;   // node 1  (level 1)
            mk |= (h1 > (double)Tf[2])  ?     4u : 0u;   // node 2
            mk |= (h2 > (double)Tf[3])  ?     8u : 0u;   // node 3  (level 2)
            mk |= (h2 > (double)Tf[4])  ?    16u : 0u;   // node 4
            mk |= (h2 > (double)Tf[5])  ?    32u : 0u;   // node 5
            mk |= (h2 > (double)Tf[6])  ?    64u : 0u;   // node 6
            mk |= (h3 > (double)Tf[7])  ?   128u : 0u;   // node 7  (level 3)
            mk |= (h3 > (double)Tf[8])  ?   256u : 0u;   // node 8
            mk |= (h3 > (double)Tf[9])  ?   512u : 0u;   // node 9
            mk |= (h3 > (double)Tf[10]) ?  1024u : 0u;   // node 10
            mk |= (h3 > (double)Tf[11]) ?  2048u : 0u;   // node 11
            mk |= (h3 > (double)Tf[12]) ?  4096u : 0u;   // node 12
            mk |= (h3 > (double)Tf[13]) ?  8192u : 0u;   // node 13
            mk |= (h3 > (double)Tf[14]) ? 16384u : 0u;   // node 14
            int p =       (int)(mk & 1u);
            p = 2 * p + (int)((mk >> (1 + p)) & 1u);
            p = 2 * p + (int)((mk >> (3 + p)) & 1u);
            p = 2 * p + (int)((mk >> (7 + p)) & 1u);

            // nibble-pack 8 codes/u32 across the cB-octet; 2 writers per row
            uint32_t v = (uint32_t)p << (4 * (cB & 7));
            v |= __shfl_xor(v, 1);
            v |= __shfl_xor(v, 2);
            v |= __shfl_xor(v, 4);
            if ((cB & 7) == 0)
                sCodes[(w * 64 + p16 * 16 + lr) * 2 + (cB >> 3)] = v;
        }
    }

    // ---- coalesced codes store: lane l -> row wave_row0 + l (8B each) ----
    const uint2 cv = ((const uint2*)sCodes)[w * 64 + lane];
    ((uint2*)codes)[wave_row0 + lane] = cv;
}

// --------------------------------------------------------------- K2: gather
__global__ __launch_bounds__(256, 2) void halut_gather(
    const float* __restrict__ L,
    const uint32_t* __restrict__ codes,
    float* __restrict__ out)
{
    __shared__ uint32_t sLut[8192];   // 32KB f16 LUT; reused as epilogue staging

    const int tid = threadIdx.x;

    // ---- stage f16 LUT: phys uint2 idx = i*512 + col*2 + mh (col = tid) ----
    {
        uint4* dst = (uint4*)sLut;                 // uint4 idx = i*256 + tid
        #pragma unroll
        for (int i = 0; i < 8; ++i) {
            uint32_t wv[4];
            #pragma unroll
            for (int mh2 = 0; mh2 < 2; ++mh2) {
                const int mb = mh2 * 32 + 4 * i;
                const float fa = L[(mb + 0) * 256 + tid];
                const float fb = L[(mb + 1) * 256 + tid];
                const float fc = L[(mb + 2) * 256 + tid];
                const float fd = L[(mb + 3) * 256 + tid];
                wv[mh2*2+0] = ((uint32_t)__half_as_ushort(__float2half_rn(fb)) << 16)
                            |  (uint32_t)__half_as_ushort(__float2half_rn(fa));
                wv[mh2*2+1] = ((uint32_t)__half_as_ushort(__float2half_rn(fd)) << 16)
                            |  (uint32_t)__half_as_ushort(__float2half_rn(fc));
            }
            dst[i * 256 + tid] = make_uint4(wv[0], wv[1], wv[2], wv[3]);
        }
    }
    __syncthreads();

    // ---- gather: 2 thr/row, bank-exact 2-way-free b64 reads (R15 verbatim) ----
    const int lr  = tid >> 1;         // 0..127
    const int mh  = tid & 1;          // m-half
    const int row = blockIdx.x * 128 + lr;
    const uint2 cw = ((const uint2*)codes)[row];   // pair-broadcast, coalesced

    __half2 acc2[16];
    #pragma unroll
    for (int k = 0; k < 16; ++k) acc2[k] = __floats2half2_rn(0.f, 0.f);

    const uint2* lut2 = (const uint2*)sLut;
    #pragma unroll 4
    for (int c = 0; c < 16; ++c) {
        const uint32_t cdw = (c < 8) ? cw.x : cw.y;
        const int p    = (int)((cdw >> (4 * (c & 7))) & 15u);
        const int col2 = (c * 16 + p) * 2 + mh;
        #pragma unroll
        for (int i = 0; i < 8; ++i) {             // m-quad = mh*8+i
            const uint2 uv = lut2[i * 512 + col2];
            acc2[2*i]   = __hadd2(acc2[2*i],   *(const __half2*)&uv.x);
            acc2[2*i+1] = __hadd2(acc2[2*i+1], *(const __half2*)&uv.y);
        }
    }

    // ---- epilogue: swizzled LDS transpose (proven), 128 rows, one pass ----
    __syncthreads();                  // all gathers done; LUT region dead
    float* sO = (float*)sLut;         // [128 rows][64 m], 16B-chunk swizzle
    #pragma unroll
    for (int k2 = 0; k2 < 8; ++k2) {
        const int ch = mh * 8 + k2;   // global float4 chunk = m/4
        const float4 v = make_float4(__low2float (acc2[2*k2]),
                                     __high2float(acc2[2*k2]),
                                     __low2float (acc2[2*k2+1]),
                                     __high2float(acc2[2*k2+1]));
        *(float4*)&sO[(lr << 6) + ((ch ^ (lr & 15)) << 2)] = v;
    }
    __syncthreads();

    float4* op = (float4*)(out + (size_t)blockIdx.x * (128 * 64));
    #pragma unroll
    for (int j = 0; j < 8; ++j) {     // 2048 float4 = 32 KiB, contiguous
        const int F  = tid + (j << 8);
        const int r2 = F >> 4;
        const int m2 = F & 15;
        op[F] = *(const float4*)&sO[(r2 << 6) + ((m2 ^ (r2 & 15)) << 2)];
    }
}

extern "C" void kernel_launch(void* const* d_in, const int* in_sizes, int n_in,
                              void* d_out, int out_size, void* d_ws, size_t ws_size,
                              hipStream_t stream) {
    const float* I = (const float*)d_in[0];
    const float* A = (const float*)d_in[1];
    const float* T = (const float*)d_in[2];
    const float* L = (const float*)d_in[3];
    float* outp = (float*)d_out;
    uint32_t* codes = (uint32_t*)d_ws;   // uint2 per row = 1 MiB

    halut_codes <<<NROWS / 256, 256, 0, stream>>>(I, A, T, codes);
    halut_gather<<<NROWS / 128, 256, 0, stream>>>(L, codes, outp);
}

// Round 17
// 32.625 us; speedup vs baseline: 1.0355x; 1.0355x over previous
//
#include <hip/hip_runtime.h>
#include <hip/hip_fp16.h>

// HalutMatmul forward on MI355X.
// Per row n: h[c][p] = sum_d I[n, c*9+d] * A[c][d][p]   (c=0..15, p=0..3)
//            code_c  = 4-level tree descent: bit_l = (h[c][l] > T[c*15 + node_l])
//            out[n][m] = sum_c L[m][c][code_c]
//
// Round-17: instruction-cache hypothesis. R3-R16: 8 structures, every pipe
// attacked, all 27-34us, all profiles show ALL pipes idle and occupancy-
// insensitive. Unconsidered resource fitting that signature: L1I. All prior
// kernels were mega-unrolled (~25-40KB straight-line code, no loop reuse ->
// I$ thrash starves every pipe; more waves = more fetch pressure, so TLP
// can't help). This kernel: identical algorithm to R15, ~5KB code:
//  - hash pass-loop ROLLED (8 iters), gather c-loop ROLLED (16 iters),
//    staging/store loops rolled; only register-array-indexing loops unrolled
//    (rule #20: dynamic-indexed reg arrays spill to scratch).
//  - codes nibble-packed to u64 -> rolled gather extracts p by variable shift.
//  - f32 hash + 1e-3 guard + f64 fallback (codes bit-exact, absmax 0.0039).

#define NROWS (1024 * 128)

typedef __attribute__((ext_vector_type(2))) float f32x2;

__global__ __launch_bounds__(256, 2) void halut_fwd(
    const float* __restrict__ I,
    const float* __restrict__ A,
    const float* __restrict__ T,
    const float* __restrict__ L,
    float* __restrict__ out)
{
    __shared__ uint32_t sLut[8192];   // 32KB f16 LUT; reused as epilogue staging
    __shared__ uint32_t sCodes[256];  // 128 rows x 2 u32 (16 codes, 4b each)

    const int tid  = threadIdx.x;
    const int w    = tid >> 6;
    const int lane = tid & 63;
    const int cB   = lane & 15;       // hash: codebook
    const int g    = lane >> 4;       // hash: row-in-pass

    // ---- per-lane constants: codebook cB's A and T in VGPRs ----
    f32x2 a01[9], a23[9];
    {
        const float4* ap4 = (const float4*)(A + cB * 36);   // 144B-aligned
        #pragma unroll
        for (int i = 0; i < 9; ++i) {
            const float4 v = ap4[i];
            a01[i] = (f32x2){v.x, v.y};
            a23[i] = (f32x2){v.z, v.w};
        }
    }
    float Tf[15];
    #pragma unroll
    for (int j = 0; j < 15; ++j) Tf[j] = T[cB * 15 + j];

    // ---- stage f16 LUT (rolled): phys uint2 idx = i*512 + col*2 + mh ----
    #pragma unroll 1
    for (int i = 0; i < 8; ++i) {
        uint32_t wv[4];
        #pragma unroll
        for (int mh2 = 0; mh2 < 2; ++mh2) {
            const int mb = mh2 * 32 + 4 * i;
            const float fa = L[(mb + 0) * 256 + tid];
            const float fb = L[(mb + 1) * 256 + tid];
            const float fc = L[(mb + 2) * 256 + tid];
            const float fd = L[(mb + 3) * 256 + tid];
            wv[mh2*2+0] = ((uint32_t)__half_as_ushort(__float2half_rn(fb)) << 16)
                        |  (uint32_t)__half_as_ushort(__float2half_rn(fa));
            wv[mh2*2+1] = ((uint32_t)__half_as_ushort(__float2half_rn(fd)) << 16)
                        |  (uint32_t)__half_as_ushort(__float2half_rn(fc));
        }
        ((uint4*)sLut)[i * 256 + tid] = make_uint4(wv[0], wv[1], wv[2], wv[3]);
    }
    __syncthreads();

    // ---- hash: ROLLED 8 passes x 4 rows, direct global reads ----
    const int brow0 = blockIdx.x * 128;
    const float* gb = I + (size_t)(brow0 + w * 32 + g) * 144 + cB * 9;

    #pragma unroll 1
    for (int ps = 0; ps < 8; ++ps) {
        const float* xp = gb + ps * 576;
        float xv[9];
        #pragma unroll
        for (int d = 0; d < 9; ++d) xv[d] = xp[d];

        f32x2 h01 = (f32x2){0.f, 0.f}, h23 = (f32x2){0.f, 0.f};
        #pragma unroll
        for (int d = 0; d < 9; ++d) {
            const f32x2 xx = (f32x2){xv[d], xv[d]};
            h01 = __builtin_elementwise_fma(xx, a01[d], h01);
            h23 = __builtin_elementwise_fma(xx, a23[d], h23);
        }
        const float hh[4] = {h01.x, h01.y, h23.x, h23.y};
        uint32_t mk = 0, bl = 0;
        #pragma unroll
        for (int j = 0; j < 15; ++j) {
            const int lv = (j == 0) ? 0 : (j < 3) ? 1 : (j < 7) ? 2 : 3;
            const float b = hh[lv] - Tf[j];
            mk |= (b > 0.f) ? (1u << j) : 0u;
            bl |= (fabsf(b) < 1e-3f) ? 1u : 0u;
        }
        if (bl) {   // rare borderline: exact f64, FMA order of rounds 1-10
            double h0 = 0.0, h1 = 0.0, h2 = 0.0, h3 = 0.0;
            #pragma unroll
            for (int d = 0; d < 9; ++d) {
                const double x = (double)xv[d];
                h0 = fma(x, (double)a01[d].x, h0);
                h1 = fma(x, (double)a01[d].y, h1);
                h2 = fma(x, (double)a23[d].x, h2);
                h3 = fma(x, (double)a23[d].y, h3);
            }
            const double hd[4] = {h0, h1, h2, h3};
            mk = 0;
            #pragma unroll
            for (int j = 0; j < 15; ++j) {
                const int lv = (j == 0) ? 0 : (j < 3) ? 1 : (j < 7) ? 2 : 3;
                mk |= (hd[lv] > (double)Tf[j]) ? (1u << j) : 0u;
            }
        }
        int p =       (int)(mk & 1u);
        p = 2 * p + (int)((mk >> (1 + p)) & 1u);
        p = 2 * p + (int)((mk >> (3 + p)) & 1u);
        p = 2 * p + (int)((mk >> (7 + p)) & 1u);

        // nibble-pack 8 codes/u32 across the cB-octet; 2 writers per row
        uint32_t v = (uint32_t)p << (4 * (cB & 7));
        v |= __shfl_xor(v, 1);
        v |= __shfl_xor(v, 2);
        v |= __shfl_xor(v, 4);
        if ((cB & 7) == 0)
            sCodes[(w * 32 + ps * 4 + g) * 2 + (cB >> 3)] = v;
    }

    // ---- gather (ROLLED c-loop): 2 thr/row, bank-exact 2-way-free b64 ----
    const int lr = tid >> 1;          // 0..127; wave w gathers rows it hashed
    const int mh = tid & 1;           // m-half
    const uint2 cwv = ((const uint2*)sCodes)[lr];   // same-wave: no barrier
    const uint64_t cc = (uint64_t)cwv.x | ((uint64_t)cwv.y << 32);

    __half2 acc2[16];
    #pragma unroll
    for (int k = 0; k < 16; ++k) acc2[k] = __floats2half2_rn(0.f, 0.f);

    const uint2* lut2 = (const uint2*)sLut;
    #pragma unroll 1
    for (int c = 0; c < 16; ++c) {
        const int p    = (int)((cc >> (4 * c)) & 15u);
        const int col2 = ((c << 4) + p) * 2 + mh;
        #pragma unroll
        for (int i = 0; i < 8; ++i) {             // m-quad = mh*8+i
            const uint2 uv = lut2[i * 512 + col2];
            acc2[2*i]   = __hadd2(acc2[2*i],   *(const __half2*)&uv.x);
            acc2[2*i+1] = __hadd2(acc2[2*i+1], *(const __half2*)&uv.y);
        }
    }

    // ---- epilogue: swizzled LDS transpose (proven), 128 rows, one pass ----
    __syncthreads();                  // all gathers done; LUT region dead
    float* sO = (float*)sLut;         // [128 rows][64 m], 16B-chunk swizzle
    #pragma unroll
    for (int k2 = 0; k2 < 8; ++k2) {  // unrolled: static acc2 index (rule #20)
        const int ch = mh * 8 + k2;
        const float4 v = make_float4(__low2float (acc2[2*k2]),
                                     __high2float(acc2[2*k2]),
                                     __low2float (acc2[2*k2+1]),
                                     __high2float(acc2[2*k2+1]));
        *(float4*)&sO[(lr << 6) + ((ch ^ (lr & 15)) << 2)] = v;
    }
    __syncthreads();

    float4* op = (float4*)(out + (size_t)blockIdx.x * (128 * 64));
    #pragma unroll 1
    for (int j = 0; j < 8; ++j) {     // 2048 float4 = 32 KiB, contiguous
        const int F  = tid + (j << 8);
        const int r2 = F >> 4;
        const int m2 = F & 15;
        op[F] = *(const float4*)&sO[(r2 << 6) + ((m2 ^ (r2 & 15)) << 2)];
    }
}

extern "C" void kernel_launch(void* const* d_in, const int* in_sizes, int n_in,
                              void* d_out, int out_size, void* d_ws, size_t ws_size,
                              hipStream_t stream) {
    const float* I = (const float*)d_in[0];
    const float* A = (const float*)d_in[1];
    const float* T = (const float*)d_in[2];
    const float* L = (const float*)d_in[3];
    float* outp = (float*)d_out;

    const int nblocks = NROWS / 128;   // 1024 blocks x 256 threads
    halut_fwd<<<nblocks, 256, 0, stream>>>(I, A, T, L, outp);
}

// Round 18
// 27.132 us; speedup vs baseline: 1.2451x; 1.2024x over previous
//
#include <hip/hip_runtime.h>
#include <hip/hip_fp16.h>

// HalutMatmul forward on MI355X — FINAL (round-10 configuration, best of 17
// rounds at 27.4 us; rounds 11-17 falsified VALU/occupancy/MFMA/split/I$
// hypotheses, all landing 29-34 us).
//
// Per row n: h[c][p] = sum_d I[n, c*9+d] * A[c][d][p]   (c=0..15, p=0..3)
//            code_c  = 4-level tree descent: bit_l = (h[c][l] > T[c*15 + node_l])
//            out[n][m] = sum_c L[m][c][code_c]
//
// Structure:
//  - lane (g,c) holds codebook c's A (36 f32) + T (15 f32) in VGPRs, loaded
//    once -> zero A/T LDS traffic in the hash loop.
//  - hash: 4 superphases x (stage 16 rows coalesced into wave-private LDS,
//    4 passes x 4 rows); f64 FMA chain -> codes exact vs the f64 reference
//    order established in round 1 (absmax limited only by f16 LUT: 0.0039).
//  - codes hand off via 4KB LDS byte array (same-wave, no extra barrier).
//  - gather: f16 LUT uint4[m/8][col], 8 ds_read_b128 per codebook, 16-slot
//    spread = 2-way bank aliasing (free); v_pk_add_f16 accumulate.
//  - epilogue: swizzled LDS transpose (measured 0 conflicts) -> fully
//    contiguous float4 stores (WRITE_SIZE = 32768 KB exactly).

#define NROWS (1024 * 128)

__global__ __launch_bounds__(256, 2) void halut_fwd(
    const float* __restrict__ I,
    const float* __restrict__ A,
    const float* __restrict__ T,
    const float* __restrict__ L,
    float* __restrict__ out)
{
    // 32KB f16 LUT (reused as epilogue staging) + 4x9KB per-wave I tiles + 4KB codes
    __shared__ uint32_t sLut[8192];
    __shared__ float    sStage[4][2304];   // wave-private: 16 rows x 144 f32
    __shared__ uint8_t  sCodes[4096];      // [256 block-rows][16 c]

    const int tid  = threadIdx.x;
    const int w    = tid >> 6;
    const int lane = tid & 63;

    // ---- per-lane constants: lane (g,c) owns codebook cB ----
    const int cB = lane & 15;              // codebook (hash phase)
    const int g  = lane >> 4;              // row-in-pass (hash phase)
    float Af[36];
    {
        const float4* ap4 = (const float4*)(A + cB * 36);   // 144B-aligned
        #pragma unroll
        for (int i = 0; i < 9; ++i) {
            const float4 v = ap4[i];
            Af[4*i+0] = v.x; Af[4*i+1] = v.y; Af[4*i+2] = v.z; Af[4*i+3] = v.w;
        }
    }
    float Tf[15];
    #pragma unroll
    for (int j = 0; j < 15; ++j) Tf[j] = T[cB * 15 + j];

    // ---- stage f16 LUT: thread t owns column col = t ----
    {
        uint4* lut4 = (uint4*)sLut;
        #pragma unroll
        for (int q = 0; q < 8; ++q) {
            uint32_t wv[4];
            #pragma unroll
            for (int e = 0; e < 4; ++e) {
                const float fa = L[(8*q + 2*e)     * 256 + tid];
                const float fb = L[(8*q + 2*e + 1) * 256 + tid];
                wv[e] = ((uint32_t)__half_as_ushort(__float2half_rn(fb)) << 16)
                      |  (uint32_t)__half_as_ushort(__float2half_rn(fa));
            }
            lut4[q * 256 + tid] = make_uint4(wv[0], wv[1], wv[2], wv[3]);
        }
    }
    __syncthreads();   // LUT visible to all waves

    // ---- hash superphases: 4 x (stage 16 rows coalesced, 4 passes x 4 rows) ----
    const int wave_row0 = blockIdx.x * 256 + w * 64;   // global row base of wave
    const float4* Isrc = (const float4*)I;
    float4* st4 = (float4*)sStage[w];

    float4 nbuf[9];
    #pragma unroll
    for (int i = 0; i < 9; ++i)
        nbuf[i] = Isrc[(size_t)wave_row0 * 36 + i * 64 + lane];

    #pragma unroll
    for (int p16 = 0; p16 < 4; ++p16) {
        #pragma unroll
        for (int i = 0; i < 9; ++i) st4[i * 64 + lane] = nbuf[i];   // write-late
        if (p16 < 3) {                                               // issue-early
            #pragma unroll
            for (int i = 0; i < 9; ++i)
                nbuf[i] = Isrc[(size_t)(wave_row0 + (p16+1)*16) * 36 + i*64 + lane];
        }
        #pragma unroll
        for (int ps = 0; ps < 4; ++ps) {
            const int lr = ps * 4 + g;            // row 0..15 within chunk
            const float* xr = &sStage[w][lr * 144 + cB * 9];
            // f64 hash, same value/order as rounds 1-9 (codes bit-identical)
            double h0 = 0.0, h1 = 0.0, h2 = 0.0, h3 = 0.0;
            #pragma unroll
            for (int d = 0; d < 9; ++d) {
                const double x = (double)xr[d];
                h0 = fma(x, (double)Af[4*d+0], h0);
                h1 = fma(x, (double)Af[4*d+1], h1);
                h2 = fma(x, (double)Af[4*d+2], h2);
                h3 = fma(x, (double)Af[4*d+3], h3);
            }
            uint32_t mk = 0;
            mk |= (h0 > (double)Tf[0])  ?     1u : 0u;   // node 0  (level 0)
            mk |= (h1 > (double)Tf[1])  ?     2u : 0u;   // node 1  (level 1)
            mk |= (h1 > (double)Tf[2])  ?     4u : 0u;   // node 2
            mk |= (h2 > (double)Tf[3])  ?     8u : 0u;   // node 3  (level 2)
            mk |= (h2 > (double)Tf[4])  ?    16u : 0u;   // node 4
            mk |= (h2 > (double)Tf[5])  ?    32u : 0u;   // node 5
            mk |= (h2 > (double)Tf[6])  ?    64u : 0u;   // node 6
            mk |= (h3 > (double)Tf[7])  ?   128u : 0u;   // node 7  (level 3)
            mk |= (h3 > (double)Tf[8])  ?   256u : 0u;   // node 8
            mk |= (h3 > (double)Tf[9])  ?   512u : 0u;   // node 9
            mk |= (h3 > (double)Tf[10]) ?  1024u : 0u;   // node 10
            mk |= (h3 > (double)Tf[11]) ?  2048u : 0u;   // node 11
            mk |= (h3 > (double)Tf[12]) ?  4096u : 0u;   // node 12
            mk |= (h3 > (double)Tf[13]) ?  8192u : 0u;   // node 13
            mk |= (h3 > (double)Tf[14]) ? 16384u : 0u;   // node 14
            int p =       (int)(mk & 1u);
            p = 2 * p + (int)((mk >> (1 + p)) & 1u);
            p = 2 * p + (int)((mk >> (3 + p)) & 1u);
            p = 2 * p + (int)((mk >> (7 + p)) & 1u);
            sCodes[(w * 64 + p16 * 16 + lr) * 16 + cB] = (uint8_t)p;
        }
    }

    // ---- gather: lane = row (same-wave codes, no barrier needed) ----
    const uint4 cw = *(const uint4*)&sCodes[tid * 16];   // my row's 16 codes
    const uint32_t cd0 = cw.x, cd1 = cw.y, cd2 = cw.z, cd3 = cw.w;

    __half2 acc2[32];
    #pragma unroll
    for (int k = 0; k < 32; ++k) acc2[k] = __floats2half2_rn(0.f, 0.f);

    const uint4* lut4 = (const uint4*)sLut;
    #pragma unroll 4
    for (int c = 0; c < 16; ++c) {
        const uint32_t cdw = (c < 4) ? cd0 : (c < 8) ? cd1 : (c < 12) ? cd2 : cd3;
        const int p = (int)((cdw >> ((c & 3) * 8)) & 15u);
        const uint4* colp = lut4 + (c << 4) + p;
        #pragma unroll
        for (int q = 0; q < 8; ++q) {
            const uint4 wv = colp[q << 8];
            acc2[q*4+0] = __hadd2(acc2[q*4+0], *(const __half2*)&wv.x);
            acc2[q*4+1] = __hadd2(acc2[q*4+1], *(const __half2*)&wv.y);
            acc2[q*4+2] = __hadd2(acc2[q*4+2], *(const __half2*)&wv.z);
            acc2[q*4+3] = __hadd2(acc2[q*4+3], *(const __half2*)&wv.w);
        }
    }

    // ---- epilogue: swizzled LDS transpose, 2 x 128 rows ----
    __syncthreads();                     // all gathers done; LUT region dead
    float* sO = (float*)sLut;            // [128 rows][64 m], 16B-chunk swizzle
    #pragma unroll
    for (int half = 0; half < 2; ++half) {
        if ((tid >> 7) == half) {        // wave-uniform branch
            const int r = tid & 127;
            #pragma unroll
            for (int ch = 0; ch < 16; ++ch) {
                const float4 v = make_float4(__low2float (acc2[2 * ch]),
                                             __high2float(acc2[2 * ch]),
                                             __low2float (acc2[2 * ch + 1]),
                                             __high2float(acc2[2 * ch + 1]));
                *(float4*)&sO[(r << 6) + ((ch ^ (r & 15)) << 2)] = v;
            }
        }
        __syncthreads();
        float4* op = (float4*)(out + (size_t)blockIdx.x * (256 * 64)
                                   + (size_t)half * (128 * 64));
        #pragma unroll
        for (int j = 0; j < 8; ++j) {    // 2048 float4 = 32 KiB, contiguous
            const int F  = tid + (j << 8);
            const int r2 = F >> 4;
            const int m2 = F & 15;
            op[F] = *(const float4*)&sO[(r2 << 6) + ((m2 ^ (r2 & 15)) << 2)];
        }
        __syncthreads();
    }
}

extern "C" void kernel_launch(void* const* d_in, const int* in_sizes, int n_in,
                              void* d_out, int out_size, void* d_ws, size_t ws_size,
                              hipStream_t stream) {
    const float* I = (const float*)d_in[0];
    const float* A = (const float*)d_in[1];
    const float* T = (const float*)d_in[2];
    const float* L = (const float*)d_in[3];
    float* outp = (float*)d_out;

    const int nblocks = NROWS / 256;   // 512 blocks x 256 threads
    halut_fwd<<<nblocks, 256, 0, stream>>>(I, A, T, L, outp);
}